// Round 1
// baseline (407.892 us; speedup 1.0000x reference)
//
#include <hip/hip_runtime.h>

// GRU cell, B=8192, IN=H=1024, OUT=512.
// Strategy: cast everything to bf16 once (fp32 accuracy threshold is 8e-2 —
// bf16 MFMA error ~2e-3), then three m97-style 128x128-tile MFMA GEMMs:
//   1) [B,2048] @ W_zr^T (N=2048, z and r fused)  -> z (fp32 scratch), XRH[:,1024:]=bf16(r*h)
//   2) [B,2048] @ W_h^T  (N=1024)                 -> hidden (fp32 out) + HID bf16
//   3) [B,1024] @ W_o^T  (N=512)                  -> output (fp32 out)
// Both GEMM operands are K-major (A·B^T), so A-tiles and W-tiles stage
// identically via global_load_lds width=16 (wave-uniform base + lane*16).

typedef __bf16 bf16x8 __attribute__((ext_vector_type(8)));
typedef float floatx4 __attribute__((ext_vector_type(4)));

__device__ __forceinline__ unsigned short f2bf(float f) {
  // round-to-nearest-even fp32 -> bf16 (inputs are finite; no NaN handling)
  unsigned int u = __float_as_uint(f);
  u += 0x7fffu + ((u >> 16) & 1u);
  return (unsigned short)(u >> 16);
}

__device__ __forceinline__ void gld16(const void* g, void* l) {
  // async global->LDS, 16B per lane; LDS dest = wave-uniform base + lane*16
  __builtin_amdgcn_global_load_lds(
      (__attribute__((address_space(1))) void*)g,
      (__attribute__((address_space(3))) void*)l, 16, 0, 0);
}

// x[B,1024], h[B,1024] fp32 -> XH[:,0:1024]=bf16(x), XH[:,1024:]=bf16(h),
// XRH[:,0:1024]=bf16(x). One float4 of x and one of h per thread.
__global__ void k_pack_xh(const float* __restrict__ x, const float* __restrict__ h,
                          unsigned short* __restrict__ XH,
                          unsigned short* __restrict__ XRH) {
  int t = blockIdx.x * blockDim.x + threadIdx.x;  // 0 .. B*1024/4
  int row = t >> 8;                               // 256 float4 per row
  int c4 = (t & 255) << 2;
  float4 xv = reinterpret_cast<const float4*>(x)[t];
  float4 hv = reinterpret_cast<const float4*>(h)[t];
  ushort4 xb = make_ushort4(f2bf(xv.x), f2bf(xv.y), f2bf(xv.z), f2bf(xv.w));
  ushort4 hb = make_ushort4(f2bf(hv.x), f2bf(hv.y), f2bf(hv.z), f2bf(hv.w));
  size_t base = (size_t)row * 2048 + c4;
  *reinterpret_cast<ushort4*>(XH + base) = xb;
  *reinterpret_cast<ushort4*>(XRH + base) = xb;
  *reinterpret_cast<ushort4*>(XH + base + 1024) = hb;
}

// generic fp32 -> bf16 convert, float4 granularity
__global__ void k_cvt(const float* __restrict__ src, unsigned short* __restrict__ dst,
                      int n4) {
  int t = blockIdx.x * blockDim.x + threadIdx.x;
  if (t >= n4) return;
  float4 v = reinterpret_cast<const float4*>(src)[t];
  ushort4 b = make_ushort4(f2bf(v.x), f2bf(v.y), f2bf(v.z), f2bf(v.w));
  reinterpret_cast<ushort4*>(dst)[t] = b;
}

// C = A[Mx K] * Bw[N x K]^T, 128x128 block tile, BK=32, 4 waves of 4x4
// 16x16x32 bf16 MFMA. EPI: 0 = z/r gates, 1 = candidate+combine, 2 = output.
template <int EPI>
__global__ __launch_bounds__(256) void k_gemm(
    const unsigned short* __restrict__ A, const unsigned short* __restrict__ Bw,
    int K, const float* __restrict__ bias1, const float* __restrict__ bias2,
    const float* __restrict__ hprev, float* __restrict__ Zbuf,
    unsigned short* __restrict__ XRH, float* __restrict__ outHid,
    unsigned short* __restrict__ HID, float* __restrict__ outO) {
  __shared__ __align__(16) unsigned short As[128 * 32];
  __shared__ __align__(16) unsigned short Bs[128 * 32];

  const int tid = threadIdx.x;
  const int wave = tid >> 6;
  const int lane = tid & 63;
  const int bm = blockIdx.x;
  const int bn = blockIdx.y;
  const int wm = (wave >> 1) << 6;  // wave's 64-row sub-tile
  const int wn = (wave & 1) << 6;   // wave's 64-col sub-tile
  const int quad = lane >> 4;
  const int l16 = lane & 15;

  // staging: each wave fills 2x1KB chunks of As and Bs.
  // chunk layout: LDS row-major [128][32] bf16, 64B/row; lane i of a chunk
  // covers row base+ (i>>2), k-chunk (i&3)*8 (16B) — contiguous in lane order.
  const int r0 = (wave << 5) + (lane >> 2);
  const int kc = (lane & 3) << 3;
  const unsigned short* gA = A + (size_t)(bm * 128 + r0) * K + kc;
  const unsigned short* gB = Bw + (size_t)(bn * 128 + r0) * K + kc;
  unsigned short* lA = As + (wave << 10);  // wave*2048 bytes
  unsigned short* lB = Bs + (wave << 10);
  const size_t stride16 = (size_t)16 * K;

  floatx4 zero4 = {0.f, 0.f, 0.f, 0.f};
  floatx4 acc[4][4];
#pragma unroll
  for (int i = 0; i < 4; ++i)
#pragma unroll
    for (int j = 0; j < 4; ++j) acc[i][j] = zero4;

  for (int k0 = 0; k0 < K; k0 += 32) {
    __syncthreads();  // previous iter's ds_reads done before overwrite
    gld16(gA, lA);
    gld16(gA + stride16, lA + 512);
    gld16(gB, lB);
    gld16(gB + stride16, lB + 512);
    gA += 32;
    gB += 32;
    __syncthreads();  // drains vmcnt -> LDS tiles visible
    bf16x8 af[4], bfg[4];
#pragma unroll
    for (int mt = 0; mt < 4; ++mt)
      af[mt] = *reinterpret_cast<const bf16x8*>(As + ((wm + mt * 16 + l16) << 5) +
                                                (quad << 3));
#pragma unroll
    for (int nt = 0; nt < 4; ++nt)
      bfg[nt] = *reinterpret_cast<const bf16x8*>(Bs + ((wn + nt * 16 + l16) << 5) +
                                                 (quad << 3));
#pragma unroll
    for (int mt = 0; mt < 4; ++mt)
#pragma unroll
      for (int nt = 0; nt < 4; ++nt)
        acc[mt][nt] =
            __builtin_amdgcn_mfma_f32_16x16x32_bf16(af[mt], bfg[nt], acc[mt][nt], 0, 0, 0);
  }

  // Epilogue. C/D layout: col = lane&15, row = quad*4 + reg.
#pragma unroll
  for (int nt = 0; nt < 4; ++nt) {
    const int n = bn * 128 + wn + nt * 16 + l16;
    if (EPI == 0) {
      // N=2048: cols 0..1023 -> z gate, 1024..2047 -> r gate (wave-uniform per block)
      const bool isz = (n < 1024);
      const int nn = isz ? n : n - 1024;
      const float bb = isz ? bias1[nn] : bias2[nn];
#pragma unroll
      for (int mt = 0; mt < 4; ++mt) {
#pragma unroll
        for (int r = 0; r < 4; ++r) {
          const int m = bm * 128 + wm + mt * 16 + quad * 4 + r;
          float v = acc[mt][nt][r] + bb;
          float s = 1.f / (1.f + __expf(-v));
          if (isz) {
            Zbuf[(size_t)m * 1024 + nn] = s;  // fp32: avoid gate quantization
          } else {
            XRH[(size_t)m * 2048 + 1024 + nn] =
                f2bf(s * hprev[(size_t)m * 1024 + nn]);
          }
        }
      }
    } else if (EPI == 1) {
      const float bb = bias1[n];
#pragma unroll
      for (int mt = 0; mt < 4; ++mt) {
#pragma unroll
        for (int r = 0; r < 4; ++r) {
          const int m = bm * 128 + wm + mt * 16 + quad * 4 + r;
          float v = acc[mt][nt][r] + bb;
          float e = __expf(-2.f * v);  // |v| <~ 10, no overflow
          float th = (1.f - e) / (1.f + e);
          float z = Zbuf[(size_t)m * 1024 + n];
          float hold = hprev[(size_t)m * 1024 + n];
          float hid = hold + z * (th - hold);  // (1-z)*h + z*h~
          outHid[(size_t)m * 1024 + n] = hid;
          HID[(size_t)m * 1024 + n] = f2bf(hid);
        }
      }
    } else {
      const float bb = bias1[n];
#pragma unroll
      for (int mt = 0; mt < 4; ++mt) {
#pragma unroll
        for (int r = 0; r < 4; ++r) {
          const int m = bm * 128 + wm + mt * 16 + quad * 4 + r;
          outO[(size_t)m * 512 + n] = acc[mt][nt][r] + bb;
        }
      }
    }
  }
}

extern "C" void kernel_launch(void* const* d_in, const int* in_sizes, int n_in,
                              void* d_out, int out_size, void* d_ws, size_t ws_size,
                              hipStream_t stream) {
  const float* x = (const float*)d_in[0];
  const float* h = (const float*)d_in[1];
  const float* Wz = (const float*)d_in[2];
  const float* bz = (const float*)d_in[3];
  const float* Wr = (const float*)d_in[4];
  const float* br = (const float*)d_in[5];
  const float* Wh = (const float*)d_in[6];
  const float* bh = (const float*)d_in[7];
  const float* Wo = (const float*)d_in[8];
  const float* bo = (const float*)d_in[9];

  float* outO = (float*)d_out;                    // [8192,512]
  float* outHid = outO + (size_t)8192 * 512;      // [8192,1024]

  // workspace layout (112 MiB total)
  char* ws = (char*)d_ws;
  const size_t MB = 1u << 20;
  unsigned short* XH = (unsigned short*)(ws + 0 * MB);    // [8192][2048] bf16, 32M
  unsigned short* XRH = (unsigned short*)(ws + 32 * MB);  // [8192][2048] bf16, 32M
  unsigned short* WZR = (unsigned short*)(ws + 64 * MB);  // [2048][2048] bf16,  8M
  unsigned short* WHb = (unsigned short*)(ws + 72 * MB);  // [1024][2048] bf16,  4M
  unsigned short* WOb = (unsigned short*)(ws + 76 * MB);  // [512][1024]  bf16,  1M
  float* Zb = (float*)(ws + 80 * MB);                     // [8192][1024] fp32, 32M
  unsigned short* HID = XH;  // XH is dead after the z/r GEMM — reuse as bf16 hidden

  // stage conversions
  k_pack_xh<<<8192, 256, 0, stream>>>(x, h, XH, XRH);
  k_cvt<<<2048, 256, 0, stream>>>(Wz, WZR, (1024 * 2048) / 4);
  k_cvt<<<2048, 256, 0, stream>>>(Wr, WZR + 1024 * 2048, (1024 * 2048) / 4);
  k_cvt<<<2048, 256, 0, stream>>>(Wh, WHb, (1024 * 2048) / 4);
  k_cvt<<<512, 256, 0, stream>>>(Wo, WOb, (512 * 1024) / 4);

  // GEMM 1: z and r gates fused (N=2048)
  k_gemm<0><<<dim3(64, 16), 256, 0, stream>>>(XH, WZR, 2048, bz, br, h, Zb, XRH,
                                              nullptr, nullptr, nullptr);
  // GEMM 2: candidate + GRU combine (N=1024)
  k_gemm<1><<<dim3(64, 8), 256, 0, stream>>>(XRH, WHb, 2048, bh, nullptr, h, Zb,
                                             nullptr, outHid, HID, nullptr);
  // GEMM 3: output projection (N=512)
  k_gemm<2><<<dim3(64, 4), 256, 0, stream>>>(HID, WOb, 1024, bo, nullptr, nullptr,
                                             nullptr, nullptr, nullptr, nullptr, outO);
}

// Round 4
// 372.753 us; speedup vs baseline: 1.0943x; 1.0943x over previous
//
#include <hip/hip_runtime.h>

// GRU cell, B=8192, IN=H=1024, OUT=512 — bf16 MFMA pipeline.
// R4: GEMM3 call now has the full 11 args (4 + 6 nullptrs + outO).
// BK=64 + XOR-swizzled LDS (conflict-free ds_read_b128), TM=64 for GEMM3.
//
// LDS layout: tile [TM][64] bf16, row = 128 B = 8 chunks of 16 B. Chunk c of
// row r lives at slot (c ^ (r & 7)) — staged by swizzling the *global* source
// address per lane (global_load_lds dest is wave-uniform base + lane*16, so
// the LDS side cannot scatter; the global side can). Fragment reads at fixed
// (ks,quad) then hit 8 distinct bank groups per 16-lane phase -> 2-way = free.

typedef __bf16 bf16x8 __attribute__((ext_vector_type(8)));
typedef float floatx4 __attribute__((ext_vector_type(4)));

__device__ __forceinline__ unsigned short f2bf(float f) {
  unsigned int u = __float_as_uint(f);
  u += 0x7fffu + ((u >> 16) & 1u);
  return (unsigned short)(u >> 16);
}

__device__ __forceinline__ void gld16(const void* g, void* l) {
  __builtin_amdgcn_global_load_lds(
      (__attribute__((address_space(1))) void*)g,
      (__attribute__((address_space(3))) void*)l, 16, 0, 0);
}

__global__ void k_pack_xh(const float* __restrict__ x, const float* __restrict__ h,
                          unsigned short* __restrict__ XH,
                          unsigned short* __restrict__ XRH) {
  int t = blockIdx.x * blockDim.x + threadIdx.x;
  int row = t >> 8;
  int c4 = (t & 255) << 2;
  float4 xv = reinterpret_cast<const float4*>(x)[t];
  float4 hv = reinterpret_cast<const float4*>(h)[t];
  ushort4 xb = make_ushort4(f2bf(xv.x), f2bf(xv.y), f2bf(xv.z), f2bf(xv.w));
  ushort4 hb = make_ushort4(f2bf(hv.x), f2bf(hv.y), f2bf(hv.z), f2bf(hv.w));
  size_t base = (size_t)row * 2048 + c4;
  *reinterpret_cast<ushort4*>(XH + base) = xb;
  *reinterpret_cast<ushort4*>(XRH + base) = xb;
  *reinterpret_cast<ushort4*>(XH + base + 1024) = hb;
}

__global__ void k_cvt(const float* __restrict__ src, unsigned short* __restrict__ dst,
                      int n4) {
  int t = blockIdx.x * blockDim.x + threadIdx.x;
  if (t >= n4) return;
  float4 v = reinterpret_cast<const float4*>(src)[t];
  reinterpret_cast<ushort4*>(dst)[t] =
      make_ushort4(f2bf(v.x), f2bf(v.y), f2bf(v.z), f2bf(v.w));
}

// C = A[M x K] * Bw[N x K]^T. Block tile TM x 128, BK = 64, 4 waves.
// EPI: 0 = z/r gates, 1 = candidate+combine, 2 = output projection.
template <int EPI, int TM>
__global__ __launch_bounds__(256) void k_gemm(
    const unsigned short* __restrict__ A, const unsigned short* __restrict__ Bw,
    int K, const float* __restrict__ bias1, const float* __restrict__ bias2,
    const float* __restrict__ hprev, float* __restrict__ Zbuf,
    unsigned short* __restrict__ XRH, float* __restrict__ outHid,
    unsigned short* __restrict__ HID, float* __restrict__ outO) {
  constexpr int MT = TM / 32;           // m-fragments per wave (16 rows each)
  __shared__ __align__(16) unsigned short As[TM * 64];
  __shared__ __align__(16) unsigned short Bs[128 * 64];

  const int tid = threadIdx.x;
  const int wave = tid >> 6;
  const int lane = tid & 63;
  const int bm = blockIdx.x;
  const int bn = blockIdx.y;
  const int wm = (wave >> 1) * (TM / 2);  // wave sub-tile: (TM/2) x 64
  const int wn = (wave & 1) << 6;
  const int quad = lane >> 4;
  const int l16 = lane & 15;
  const int sw = l16 & 7;

  // staging: each gld16 covers 8 rows x 64 cols. Lane -> (row = lane>>3,
  // LDS slot = lane&7, global chunk = slot ^ (row&7)).
  const int srow = lane >> 3;
  const int sc = (lane & 7) ^ srow;
  const int arow0 = wave * (TM / 4);  // wave's A rows: TM/4
  const int brow0 = wave * 32;        // wave's B rows: 32
  const unsigned short* gA = A + (size_t)(bm * TM + arow0 + srow) * K + sc * 8;
  const unsigned short* gB = Bw + (size_t)(bn * 128 + brow0 + srow) * K + sc * 8;
  const size_t row8 = (size_t)8 * K;

  floatx4 acc[MT][4];
#pragma unroll
  for (int i = 0; i < MT; ++i)
#pragma unroll
    for (int j = 0; j < 4; ++j) acc[i][j] = floatx4{0.f, 0.f, 0.f, 0.f};

  const unsigned short* ar = As + (wm + l16) * 64;
  const unsigned short* br = Bs + (wn + l16) * 64;

  for (int k0 = 0; k0 < K; k0 += 64) {
    __syncthreads();  // prior iter's ds_reads complete before overwrite
#pragma unroll
    for (int g = 0; g < TM / 32; ++g)
      gld16(gA + (size_t)g * row8, As + (arow0 + g * 8) * 64);
#pragma unroll
    for (int g = 0; g < 4; ++g)
      gld16(gB + (size_t)g * row8, Bs + (brow0 + g * 8) * 64);
    gA += 64;
    gB += 64;
    __syncthreads();  // drains vmcnt -> tiles visible
#pragma unroll
    for (int ks = 0; ks < 2; ++ks) {
      const int co = (((ks << 2) | quad) ^ sw) << 3;  // swizzled 16B chunk
      bf16x8 af[MT], bfg[4];
#pragma unroll
      for (int mt = 0; mt < MT; ++mt)
        af[mt] = *reinterpret_cast<const bf16x8*>(ar + mt * 1024 + co);
#pragma unroll
      for (int nt = 0; nt < 4; ++nt)
        bfg[nt] = *reinterpret_cast<const bf16x8*>(br + nt * 1024 + co);
#pragma unroll
      for (int mt = 0; mt < MT; ++mt)
#pragma unroll
        for (int nt = 0; nt < 4; ++nt)
          acc[mt][nt] = __builtin_amdgcn_mfma_f32_16x16x32_bf16(af[mt], bfg[nt],
                                                                acc[mt][nt], 0, 0, 0);
    }
  }

  // Epilogue. C/D layout: col = lane&15, row = quad*4 + reg.
#pragma unroll
  for (int nt = 0; nt < 4; ++nt) {
    const int n = bn * 128 + wn + nt * 16 + l16;
    if (EPI == 0) {
      const bool isz = (n < 1024);  // wave-uniform (block n-range is 128-aligned)
      const int nn = isz ? n : n - 1024;
      const float bb = isz ? bias1[nn] : bias2[nn];
#pragma unroll
      for (int mt = 0; mt < MT; ++mt) {
#pragma unroll
        for (int r = 0; r < 4; ++r) {
          const int m = bm * TM + wm + mt * 16 + quad * 4 + r;
          float v = acc[mt][nt][r] + bb;
          float s = 1.f / (1.f + __expf(-v));
          if (isz) {
            Zbuf[(size_t)m * 1024 + nn] = s;  // fp32: no gate quantization
          } else {
            XRH[(size_t)m * 2048 + 1024 + nn] =
                f2bf(s * hprev[(size_t)m * 1024 + nn]);
          }
        }
      }
    } else if (EPI == 1) {
      const float bb = bias1[n];
#pragma unroll
      for (int mt = 0; mt < MT; ++mt) {
#pragma unroll
        for (int r = 0; r < 4; ++r) {
          const int m = bm * TM + wm + mt * 16 + quad * 4 + r;
          float v = acc[mt][nt][r] + bb;
          float e = __expf(-2.f * v);
          float th = (1.f - e) / (1.f + e);
          float z = Zbuf[(size_t)m * 1024 + n];
          float hold = hprev[(size_t)m * 1024 + n];
          float hid = hold + z * (th - hold);
          outHid[(size_t)m * 1024 + n] = hid;
          HID[(size_t)m * 1024 + n] = f2bf(hid);
        }
      }
    } else {
      const float bb = bias1[n];
#pragma unroll
      for (int mt = 0; mt < MT; ++mt) {
#pragma unroll
        for (int r = 0; r < 4; ++r) {
          const int m = bm * TM + wm + mt * 16 + quad * 4 + r;
          outO[(size_t)m * 512 + n] = acc[mt][nt][r] + bb;
        }
      }
    }
  }
}

extern "C" void kernel_launch(void* const* d_in, const int* in_sizes, int n_in,
                              void* d_out, int out_size, void* d_ws, size_t ws_size,
                              hipStream_t stream) {
  const float* x = (const float*)d_in[0];
  const float* h = (const float*)d_in[1];
  const float* Wz = (const float*)d_in[2];
  const float* bz = (const float*)d_in[3];
  const float* Wr = (const float*)d_in[4];
  const float* br = (const float*)d_in[5];
  const float* Wh = (const float*)d_in[6];
  const float* bh = (const float*)d_in[7];
  const float* Wo = (const float*)d_in[8];
  const float* bo = (const float*)d_in[9];

  float* outO = (float*)d_out;                // [8192,512]
  float* outHid = outO + (size_t)8192 * 512;  // [8192,1024]

  char* ws = (char*)d_ws;
  const size_t MB = 1u << 20;
  unsigned short* XH = (unsigned short*)(ws + 0 * MB);    // [8192][2048] bf16
  unsigned short* XRH = (unsigned short*)(ws + 32 * MB);  // [8192][2048] bf16
  unsigned short* WZR = (unsigned short*)(ws + 64 * MB);  // [2048][2048] bf16
  unsigned short* WHb = (unsigned short*)(ws + 72 * MB);  // [1024][2048] bf16
  unsigned short* WOb = (unsigned short*)(ws + 76 * MB);  // [512][1024]  bf16
  float* Zb = (float*)(ws + 80 * MB);                     // [8192][1024] fp32
  unsigned short* HID = XH;  // XH dead after GEMM1 — reuse as bf16 hidden

  k_pack_xh<<<8192, 256, 0, stream>>>(x, h, XH, XRH);
  k_cvt<<<2048, 256, 0, stream>>>(Wz, WZR, (1024 * 2048) / 4);
  k_cvt<<<2048, 256, 0, stream>>>(Wr, WZR + 1024 * 2048, (1024 * 2048) / 4);
  k_cvt<<<2048, 256, 0, stream>>>(Wh, WHb, (1024 * 2048) / 4);
  k_cvt<<<512, 256, 0, stream>>>(Wo, WOb, (512 * 1024) / 4);

  // GEMM 1: z|r fused (N=2048) — args: A,Bw,K,b1,b2,hprev,Zbuf,XRH,outHid,HID,outO
  k_gemm<0, 128><<<dim3(64, 16), 256, 0, stream>>>(
      XH, WZR, 2048, bz, br, h, Zb, XRH, nullptr, nullptr, nullptr);
  // GEMM 2: candidate + combine (N=1024)
  k_gemm<1, 128><<<dim3(64, 8), 256, 0, stream>>>(
      XRH, WHb, 2048, bh, nullptr, h, Zb, nullptr, outHid, HID, nullptr);
  // GEMM 3: output projection (N=512), TM=64 for a 512-block grid
  k_gemm<2, 64><<<dim3(128, 4), 256, 0, stream>>>(
      HID, WOb, 1024, bo, nullptr, nullptr, nullptr, nullptr, nullptr, nullptr,
      outO);
}

// Round 5
// 348.535 us; speedup vs baseline: 1.1703x; 1.0695x over previous
//
#include <hip/hip_runtime.h>

// GRU cell, B=8192, IN=H=1024, OUT=512 — bf16 MFMA pipeline.
// R5: double-buffered K-loop (BK=32, 2x16KB LDS buffers) with raw s_barrier +
// fine-grained s_waitcnt vmcnt(N) (never 0 mid-loop): loads for tile k+1 stay
// in flight across tile k's compute, hiding the ~200-900cyc load latency that
// R4's issue->vmcnt(0)->barrier structure exposed every iteration.
// Swizzled LDS (chunk c of row r at slot c^(r&3)) keeps ds_read_b128 2-way
// conflict-free (verified: SQ_LDS_BANK_CONFLICT=0 in R4). Weight converts
// fused into one launch.

typedef __bf16 bf16x8 __attribute__((ext_vector_type(8)));
typedef float floatx4 __attribute__((ext_vector_type(4)));

__device__ __forceinline__ unsigned short f2bf(float f) {
  unsigned int u = __float_as_uint(f);
  u += 0x7fffu + ((u >> 16) & 1u);
  return (unsigned short)(u >> 16);
}

__device__ __forceinline__ void gld16(const void* g, void* l) {
  // async global->LDS, 16B/lane; LDS dest must be wave-uniform base (+lane*16)
  __builtin_amdgcn_global_load_lds(
      (__attribute__((address_space(1))) void*)g,
      (__attribute__((address_space(3))) void*)l, 16, 0, 0);
}

__global__ void k_pack_xh(const float* __restrict__ x, const float* __restrict__ h,
                          unsigned short* __restrict__ XH,
                          unsigned short* __restrict__ XRH) {
  int t = blockIdx.x * blockDim.x + threadIdx.x;
  int row = t >> 8;
  int c4 = (t & 255) << 2;
  float4 xv = reinterpret_cast<const float4*>(x)[t];
  float4 hv = reinterpret_cast<const float4*>(h)[t];
  ushort4 xb = make_ushort4(f2bf(xv.x), f2bf(xv.y), f2bf(xv.z), f2bf(xv.w));
  ushort4 hb = make_ushort4(f2bf(hv.x), f2bf(hv.y), f2bf(hv.z), f2bf(hv.w));
  size_t base = (size_t)row * 2048 + c4;
  *reinterpret_cast<ushort4*>(XH + base) = xb;
  *reinterpret_cast<ushort4*>(XRH + base) = xb;
  *reinterpret_cast<ushort4*>(XH + base + 1024) = hb;
}

// all four weight matrices in one launch: [Wz|Wr] -> WZR, Wh -> WHb, Wo -> WOb
__global__ void k_cvt_all(const float* __restrict__ Wz, const float* __restrict__ Wr,
                          const float* __restrict__ Wh, const float* __restrict__ Wo,
                          unsigned short* __restrict__ WZR,
                          unsigned short* __restrict__ WHb,
                          unsigned short* __restrict__ WOb) {
  int t = blockIdx.x * blockDim.x + threadIdx.x;  // float4 index
  const int Q = 1024 * 2048 / 4;                  // 524288 f4 per big matrix
  const float* src;
  unsigned short* dst;
  int i;
  if (t < Q) {
    src = Wz; dst = WZR; i = t;
  } else if (t < 2 * Q) {
    src = Wr; dst = WZR + 1024 * 2048; i = t - Q;
  } else if (t < 3 * Q) {
    src = Wh; dst = WHb; i = t - 2 * Q;
  } else {
    src = Wo; dst = WOb; i = t - 3 * Q;
    if (i >= 512 * 1024 / 4) return;
  }
  float4 v = reinterpret_cast<const float4*>(src)[i];
  reinterpret_cast<ushort4*>(dst)[i] =
      make_ushort4(f2bf(v.x), f2bf(v.y), f2bf(v.z), f2bf(v.w));
}

// C = A[M x K] * Bw[N x K]^T. Block tile TM x 128, BK=32 double-buffered.
// EPI: 0 = z/r gates, 1 = candidate+combine, 2 = output projection.
template <int EPI, int TM>
__global__ __launch_bounds__(256) void k_gemm(
    const unsigned short* __restrict__ A, const unsigned short* __restrict__ Bw,
    int K, const float* __restrict__ bias1, const float* __restrict__ bias2,
    const float* __restrict__ hprev, float* __restrict__ Zbuf,
    unsigned short* __restrict__ XRH, float* __restrict__ outHid,
    unsigned short* __restrict__ HID, float* __restrict__ outO) {
  constexpr int MT = TM / 32;            // m-frags per wave
  constexpr int BUF = TM * 32 + 4096;    // elems: A tile + B tile (128x32)
  constexpr int NLD = TM / 64 + 2;       // gld16 per thread per K-tile
  __shared__ __align__(16) unsigned short S[2 * BUF];

  const int tid = threadIdx.x;
  const int wave = tid >> 6;
  const int lane = tid & 63;
  const int bm = blockIdx.x;
  const int bn = blockIdx.y;
  const int wm = (wave >> 1) * (TM / 2);
  const int wn = (wave & 1) << 6;
  const int quad = lane >> 4;
  const int l16 = lane & 15;
  const int co = ((quad ^ (l16 & 3)) << 3);  // swizzled 16B chunk for reads

  // staging: one gld16 = 1KB = 16 rows x 32 cols. lane -> row lr=lane>>2,
  // LDS slot lane&3, global chunk (lane&3)^(lr&3)  (=> chunk c at slot c^(r&3))
  const int lr = lane >> 2;
  const int sc = (lane & 3) ^ (lr & 3);
  const int arow0 = wave * (TM / 4);
  const int brow0 = wave * 32;
  const unsigned short* gA = A + (size_t)(bm * TM + arow0 + lr) * K + sc * 8;
  const unsigned short* gB = Bw + (size_t)(bn * 128 + brow0 + lr) * K + sc * 8;
  const size_t row16 = (size_t)16 * K;

  floatx4 acc[MT][4];
#pragma unroll
  for (int i = 0; i < MT; ++i)
#pragma unroll
    for (int j = 0; j < 4; ++j) acc[i][j] = floatx4{0.f, 0.f, 0.f, 0.f};

  auto stage = [&](int buf, int kk) {
    unsigned short* b = S + buf * BUF;
    const unsigned short* ga = gA + (size_t)kk * 32;
    const unsigned short* gb = gB + (size_t)kk * 32;
#pragma unroll
    for (int g = 0; g < TM / 64; ++g)
      gld16(ga + g * row16, b + (arow0 + g * 16) * 32);
#pragma unroll
    for (int g = 0; g < 2; ++g)
      gld16(gb + g * row16, b + TM * 32 + (brow0 + g * 16) * 32);
  };

  auto compute = [&](int buf) {
    const unsigned short* base = S + buf * BUF;
    const unsigned short* ar = base + (wm + l16) * 32 + co;
    const unsigned short* br = base + TM * 32 + (wn + l16) * 32 + co;
    bf16x8 af[MT], bfr[4];
#pragma unroll
    for (int mt = 0; mt < MT; ++mt)
      af[mt] = *reinterpret_cast<const bf16x8*>(ar + mt * 512);
#pragma unroll
    for (int nt = 0; nt < 4; ++nt)
      bfr[nt] = *reinterpret_cast<const bf16x8*>(br + nt * 512);
#pragma unroll
    for (int mt = 0; mt < MT; ++mt)
#pragma unroll
      for (int nt = 0; nt < 4; ++nt)
        acc[mt][nt] = __builtin_amdgcn_mfma_f32_16x16x32_bf16(af[mt], bfr[nt],
                                                              acc[mt][nt], 0, 0, 0);
  };

  // barrier helpers: raw s_barrier with explicit (fine-grained) waitcnts.
  // waitN: my NLD older loads landed, newer NLD stay in flight; barrier makes
  // the whole tile visible (every wave did the same wait).
  auto waitbarN = [&]() {
    if constexpr (NLD == 4)
      asm volatile("s_waitcnt vmcnt(4)\n\ts_barrier" ::: "memory");
    else
      asm volatile("s_waitcnt vmcnt(3)\n\ts_barrier" ::: "memory");
  };
  auto waitbar0 = [&]() {
    asm volatile("s_waitcnt vmcnt(0)\n\ts_barrier" ::: "memory");
  };
  auto endbar = [&]() {  // my ds_reads done; all waves done reading the buffer
    asm volatile("s_waitcnt lgkmcnt(0)\n\ts_barrier" ::: "memory");
  };

  const int NB = K >> 5;  // K/32, always even here (64/64/32)
  stage(0, 0);
  stage(1, 1);
  for (int k = 0; k < NB; k += 2) {
    waitbarN();  // k's loads done (issued 2 sub-iters ago), k+1's in flight
    compute(0);
    endbar();
    if (k + 2 < NB) stage(0, k + 2);
    if (k + 2 < NB) waitbarN(); else waitbar0();
    compute(1);
    endbar();
    if (k + 3 < NB) stage(1, k + 3);
  }

  // Epilogue. C/D layout: col = lane&15, row = quad*4 + reg.
#pragma unroll
  for (int nt = 0; nt < 4; ++nt) {
    const int n = bn * 128 + wn + nt * 16 + l16;
    if (EPI == 0) {
      const bool isz = (n < 1024);  // wave-uniform (block n-range 128-aligned)
      const int nn = isz ? n : n - 1024;
      const float bb = isz ? bias1[nn] : bias2[nn];
#pragma unroll
      for (int mt = 0; mt < MT; ++mt) {
#pragma unroll
        for (int r = 0; r < 4; ++r) {
          const int m = bm * TM + wm + mt * 16 + quad * 4 + r;
          float v = acc[mt][nt][r] + bb;
          float s = 1.f / (1.f + __expf(-v));
          if (isz) {
            Zbuf[(size_t)m * 1024 + nn] = s;  // fp32: no gate quantization
          } else {
            XRH[(size_t)m * 2048 + 1024 + nn] =
                f2bf(s * hprev[(size_t)m * 1024 + nn]);
          }
        }
      }
    } else if (EPI == 1) {
      const float bb = bias1[n];
#pragma unroll
      for (int mt = 0; mt < MT; ++mt) {
#pragma unroll
        for (int r = 0; r < 4; ++r) {
          const int m = bm * TM + wm + mt * 16 + quad * 4 + r;
          float v = acc[mt][nt][r] + bb;
          float e = __expf(-2.f * v);
          float th = (1.f - e) / (1.f + e);
          float z = Zbuf[(size_t)m * 1024 + n];
          float hold = hprev[(size_t)m * 1024 + n];
          float hid = hold + z * (th - hold);
          outHid[(size_t)m * 1024 + n] = hid;
          HID[(size_t)m * 1024 + n] = f2bf(hid);
        }
      }
    } else {
      const float bb = bias1[n];
#pragma unroll
      for (int mt = 0; mt < MT; ++mt) {
#pragma unroll
        for (int r = 0; r < 4; ++r) {
          const int m = bm * TM + wm + mt * 16 + quad * 4 + r;
          outO[(size_t)m * 512 + n] = acc[mt][nt][r] + bb;
        }
      }
    }
  }
}

extern "C" void kernel_launch(void* const* d_in, const int* in_sizes, int n_in,
                              void* d_out, int out_size, void* d_ws, size_t ws_size,
                              hipStream_t stream) {
  const float* x = (const float*)d_in[0];
  const float* h = (const float*)d_in[1];
  const float* Wz = (const float*)d_in[2];
  const float* bz = (const float*)d_in[3];
  const float* Wr = (const float*)d_in[4];
  const float* br = (const float*)d_in[5];
  const float* Wh = (const float*)d_in[6];
  const float* bh = (const float*)d_in[7];
  const float* Wo = (const float*)d_in[8];
  const float* bo = (const float*)d_in[9];

  float* outO = (float*)d_out;                // [8192,512]
  float* outHid = outO + (size_t)8192 * 512;  // [8192,1024]

  char* ws = (char*)d_ws;
  const size_t MB = 1u << 20;
  unsigned short* XH = (unsigned short*)(ws + 0 * MB);    // [8192][2048] bf16
  unsigned short* XRH = (unsigned short*)(ws + 32 * MB);  // [8192][2048] bf16
  unsigned short* WZR = (unsigned short*)(ws + 64 * MB);  // [2048][2048] bf16
  unsigned short* WHb = (unsigned short*)(ws + 72 * MB);  // [1024][2048] bf16
  unsigned short* WOb = (unsigned short*)(ws + 76 * MB);  // [512][1024]  bf16
  float* Zb = (float*)(ws + 80 * MB);                     // [8192][1024] fp32
  unsigned short* HID = XH;  // XH dead after GEMM1 — reuse as bf16 hidden

  k_pack_xh<<<8192, 256, 0, stream>>>(x, h, XH, XRH);
  k_cvt_all<<<6656, 256, 0, stream>>>(Wz, Wr, Wh, Wo, WZR, WHb, WOb);

  // GEMM 1: z|r fused (N=2048) — args: A,Bw,K,b1,b2,hprev,Zbuf,XRH,outHid,HID,outO
  k_gemm<0, 128><<<dim3(64, 16), 256, 0, stream>>>(
      XH, WZR, 2048, bz, br, h, Zb, XRH, nullptr, nullptr, nullptr);
  // GEMM 2: candidate + combine (N=1024)
  k_gemm<1, 128><<<dim3(64, 8), 256, 0, stream>>>(
      XRH, WHb, 2048, bh, nullptr, h, Zb, nullptr, outHid, HID, nullptr);
  // GEMM 3: output projection (N=512), TM=64 for a 512-block grid
  k_gemm<2, 64><<<dim3(128, 4), 256, 0, stream>>>(
      HID, WOb, 1024, bo, nullptr, nullptr, nullptr, nullptr, nullptr, nullptr,
      outO);
}

// Round 6
// 346.773 us; speedup vs baseline: 1.1762x; 1.0051x over previous
//
#include <hip/hip_runtime.h>

// GRU cell, B=8192, IN=H=1024, OUT=512 — bf16 MFMA pipeline.
// R6: fix the BK=32 LDS swizzle. R5's slot = c^(r&3) left a 2-way phase
// conflict (row stride 64B = only 4 bank-groups): group = 4*(l16&1) +
// (quad^(l16&3)), lanes l16 and l16+4 collide -> 8.4M conflicts, LDS reads
// (the co-limiter, ~61us of GEMM1) cost 2x. New cross-row permutation for
// each 16-row x 32-col 1KB block:
//   slot(r,c) = ((r&7)^c) + 8*(r&3) + 32*(r>>3)       (bijective)
// Read phase (8 consecutive lanes, fixed quad): group = (l16&7)^quad — all 8
// distinct, the exact pattern R4 measured at SQ_LDS_BANK_CONFLICT=0.
// Staging inverts the map on the global-address side (gld16 LDS dest is
// lane-ordered and cannot scatter). Double-buffered K-loop from R5 unchanged.

typedef __bf16 bf16x8 __attribute__((ext_vector_type(8)));
typedef float floatx4 __attribute__((ext_vector_type(4)));

__device__ __forceinline__ unsigned short f2bf(float f) {
  unsigned int u = __float_as_uint(f);
  u += 0x7fffu + ((u >> 16) & 1u);
  return (unsigned short)(u >> 16);
}

__device__ __forceinline__ void gld16(const void* g, void* l) {
  // async global->LDS, 16B/lane; LDS dest = wave-uniform base + lane*16
  __builtin_amdgcn_global_load_lds(
      (__attribute__((address_space(1))) void*)g,
      (__attribute__((address_space(3))) void*)l, 16, 0, 0);
}

__global__ void k_pack_xh(const float* __restrict__ x, const float* __restrict__ h,
                          unsigned short* __restrict__ XH,
                          unsigned short* __restrict__ XRH) {
  int t = blockIdx.x * blockDim.x + threadIdx.x;
  int row = t >> 8;
  int c4 = (t & 255) << 2;
  float4 xv = reinterpret_cast<const float4*>(x)[t];
  float4 hv = reinterpret_cast<const float4*>(h)[t];
  ushort4 xb = make_ushort4(f2bf(xv.x), f2bf(xv.y), f2bf(xv.z), f2bf(xv.w));
  ushort4 hb = make_ushort4(f2bf(hv.x), f2bf(hv.y), f2bf(hv.z), f2bf(hv.w));
  size_t base = (size_t)row * 2048 + c4;
  *reinterpret_cast<ushort4*>(XH + base) = xb;
  *reinterpret_cast<ushort4*>(XRH + base) = xb;
  *reinterpret_cast<ushort4*>(XH + base + 1024) = hb;
}

// all four weight matrices in one launch: [Wz|Wr] -> WZR, Wh -> WHb, Wo -> WOb
__global__ void k_cvt_all(const float* __restrict__ Wz, const float* __restrict__ Wr,
                          const float* __restrict__ Wh, const float* __restrict__ Wo,
                          unsigned short* __restrict__ WZR,
                          unsigned short* __restrict__ WHb,
                          unsigned short* __restrict__ WOb) {
  int t = blockIdx.x * blockDim.x + threadIdx.x;  // float4 index
  const int Q = 1024 * 2048 / 4;
  const float* src;
  unsigned short* dst;
  int i;
  if (t < Q) {
    src = Wz; dst = WZR; i = t;
  } else if (t < 2 * Q) {
    src = Wr; dst = WZR + 1024 * 2048; i = t - Q;
  } else if (t < 3 * Q) {
    src = Wh; dst = WHb; i = t - 2 * Q;
  } else {
    src = Wo; dst = WOb; i = t - 3 * Q;
    if (i >= 512 * 1024 / 4) return;
  }
  float4 v = reinterpret_cast<const float4*>(src)[i];
  reinterpret_cast<ushort4*>(dst)[i] =
      make_ushort4(f2bf(v.x), f2bf(v.y), f2bf(v.z), f2bf(v.w));
}

// C = A[M x K] * Bw[N x K]^T. Block tile TM x 128, BK=32 double-buffered.
// EPI: 0 = z/r gates, 1 = candidate+combine, 2 = output projection.
template <int EPI, int TM>
__global__ __launch_bounds__(256) void k_gemm(
    const unsigned short* __restrict__ A, const unsigned short* __restrict__ Bw,
    int K, const float* __restrict__ bias1, const float* __restrict__ bias2,
    const float* __restrict__ hprev, float* __restrict__ Zbuf,
    unsigned short* __restrict__ XRH, float* __restrict__ outHid,
    unsigned short* __restrict__ HID, float* __restrict__ outO) {
  constexpr int MT = TM / 32;            // m-frags per wave
  constexpr int BUF = TM * 32 + 4096;    // elems: A tile + B tile (128x32)
  constexpr int NLD = TM / 64 + 2;       // gld16 per thread per K-tile
  __shared__ __align__(16) unsigned short S[2 * BUF];

  const int tid = threadIdx.x;
  const int wave = tid >> 6;
  const int lane = tid & 63;
  const int bm = blockIdx.x;
  const int bn = blockIdx.y;
  const int wm = (wave >> 1) * (TM / 2);
  const int wn = (wave & 1) << 6;
  const int quad = lane >> 4;
  const int l16 = lane & 15;

  // ---- staging lane map: lane i -> (row sr, k-chunk sck) inside a 16-row
  // 1KB block, inverse of slot(r,c) = ((r&7)^c) + 8*(r&3) + 32*(r>>3).
  const int g_ = lane & 7;
  const int rmid = (lane >> 3) & 3;
  const int sr = (lane >> 5) * 8 + (g_ & 4) + rmid;
  const int sck = (g_ & 3) ^ rmid;
  const int arow0 = wave * (TM / 4);
  const int brow0 = wave * 32;
  const unsigned short* gA = A + (size_t)(bm * TM + arow0 + sr) * K + sck * 8;
  const unsigned short* gB = Bw + (size_t)(bn * 128 + brow0 + sr) * K + sck * 8;
  const size_t row16 = (size_t)16 * K;

  // ---- read-side element offset within a 16-row block: slot(l16, quad)*8
  const int so = (((l16 & 7) ^ quad) << 3) + ((l16 & 3) << 6) + ((l16 >> 3) << 8);

  floatx4 acc[MT][4];
#pragma unroll
  for (int i = 0; i < MT; ++i)
#pragma unroll
    for (int j = 0; j < 4; ++j) acc[i][j] = floatx4{0.f, 0.f, 0.f, 0.f};

  auto stage = [&](int buf, int kk) {
    unsigned short* b = S + buf * BUF;
    const unsigned short* ga = gA + (size_t)kk * 32;
    const unsigned short* gb = gB + (size_t)kk * 32;
#pragma unroll
    for (int g = 0; g < TM / 64; ++g)
      gld16(ga + g * row16, b + (arow0 + g * 16) * 32);
#pragma unroll
    for (int g = 0; g < 2; ++g)
      gld16(gb + g * row16, b + TM * 32 + (brow0 + g * 16) * 32);
  };

  auto compute = [&](int buf) {
    const unsigned short* base = S + buf * BUF;
    bf16x8 af[MT], bfr[4];
#pragma unroll
    for (int mt = 0; mt < MT; ++mt)
      af[mt] = *reinterpret_cast<const bf16x8*>(base + ((wm + mt * 16) << 5) + so);
#pragma unroll
    for (int nt = 0; nt < 4; ++nt)
      bfr[nt] = *reinterpret_cast<const bf16x8*>(base + TM * 32 +
                                                 ((wn + nt * 16) << 5) + so);
#pragma unroll
    for (int mt = 0; mt < MT; ++mt)
#pragma unroll
      for (int nt = 0; nt < 4; ++nt)
        acc[mt][nt] = __builtin_amdgcn_mfma_f32_16x16x32_bf16(af[mt], bfr[nt],
                                                              acc[mt][nt], 0, 0, 0);
  };

  // raw s_barrier + fine-grained waitcnt (never vmcnt(0) mid-loop): the next
  // buffer's loads stay in flight across this buffer's compute.
  auto waitbarN = [&]() {
    if constexpr (NLD == 4)
      asm volatile("s_waitcnt vmcnt(4)\n\ts_barrier" ::: "memory");
    else
      asm volatile("s_waitcnt vmcnt(3)\n\ts_barrier" ::: "memory");
  };
  auto waitbar0 = [&]() {
    asm volatile("s_waitcnt vmcnt(0)\n\ts_barrier" ::: "memory");
  };
  auto endbar = [&]() {
    asm volatile("s_waitcnt lgkmcnt(0)\n\ts_barrier" ::: "memory");
  };

  const int NB = K >> 5;  // K/32, even for all three GEMMs
  stage(0, 0);
  stage(1, 1);
  for (int k = 0; k < NB; k += 2) {
    waitbarN();  // buffer0's loads done, buffer1's still in flight
    compute(0);
    endbar();
    if (k + 2 < NB) stage(0, k + 2);
    if (k + 2 < NB) waitbarN(); else waitbar0();
    compute(1);
    endbar();
    if (k + 3 < NB) stage(1, k + 3);
  }

  // Epilogue. C/D layout: col = lane&15, row = quad*4 + reg.
#pragma unroll
  for (int nt = 0; nt < 4; ++nt) {
    const int n = bn * 128 + wn + nt * 16 + l16;
    if (EPI == 0) {
      const bool isz = (n < 1024);  // wave-uniform (block n-range 128-aligned)
      const int nn = isz ? n : n - 1024;
      const float bb = isz ? bias1[nn] : bias2[nn];
#pragma unroll
      for (int mt = 0; mt < MT; ++mt) {
#pragma unroll
        for (int r = 0; r < 4; ++r) {
          const int m = bm * TM + wm + mt * 16 + quad * 4 + r;
          float v = acc[mt][nt][r] + bb;
          float s = 1.f / (1.f + __expf(-v));
          if (isz) {
            Zbuf[(size_t)m * 1024 + nn] = s;  // fp32: no gate quantization
          } else {
            XRH[(size_t)m * 2048 + 1024 + nn] =
                f2bf(s * hprev[(size_t)m * 1024 + nn]);
          }
        }
      }
    } else if (EPI == 1) {
      const float bb = bias1[n];
#pragma unroll
      for (int mt = 0; mt < MT; ++mt) {
#pragma unroll
        for (int r = 0; r < 4; ++r) {
          const int m = bm * TM + wm + mt * 16 + quad * 4 + r;
          float v = acc[mt][nt][r] + bb;
          float e = __expf(-2.f * v);
          float th = (1.f - e) / (1.f + e);
          float z = Zbuf[(size_t)m * 1024 + n];
          float hold = hprev[(size_t)m * 1024 + n];
          float hid = hold + z * (th - hold);
          outHid[(size_t)m * 1024 + n] = hid;
          HID[(size_t)m * 1024 + n] = f2bf(hid);
        }
      }
    } else {
      const float bb = bias1[n];
#pragma unroll
      for (int mt = 0; mt < MT; ++mt) {
#pragma unroll
        for (int r = 0; r < 4; ++r) {
          const int m = bm * TM + wm + mt * 16 + quad * 4 + r;
          outO[(size_t)m * 512 + n] = acc[mt][nt][r] + bb;
        }
      }
    }
  }
}

extern "C" void kernel_launch(void* const* d_in, const int* in_sizes, int n_in,
                              void* d_out, int out_size, void* d_ws, size_t ws_size,
                              hipStream_t stream) {
  const float* x = (const float*)d_in[0];
  const float* h = (const float*)d_in[1];
  const float* Wz = (const float*)d_in[2];
  const float* bz = (const float*)d_in[3];
  const float* Wr = (const float*)d_in[4];
  const float* br = (const float*)d_in[5];
  const float* Wh = (const float*)d_in[6];
  const float* bh = (const float*)d_in[7];
  const float* Wo = (const float*)d_in[8];
  const float* bo = (const float*)d_in[9];

  float* outO = (float*)d_out;                // [8192,512]
  float* outHid = outO + (size_t)8192 * 512;  // [8192,1024]

  char* ws = (char*)d_ws;
  const size_t MB = 1u << 20;
  unsigned short* XH = (unsigned short*)(ws + 0 * MB);    // [8192][2048] bf16
  unsigned short* XRH = (unsigned short*)(ws + 32 * MB);  // [8192][2048] bf16
  unsigned short* WZR = (unsigned short*)(ws + 64 * MB);  // [2048][2048] bf16
  unsigned short* WHb = (unsigned short*)(ws + 72 * MB);  // [1024][2048] bf16
  unsigned short* WOb = (unsigned short*)(ws + 76 * MB);  // [512][1024]  bf16
  float* Zb = (float*)(ws + 80 * MB);                     // [8192][1024] fp32
  unsigned short* HID = XH;  // XH dead after GEMM1 — reuse as bf16 hidden

  k_pack_xh<<<8192, 256, 0, stream>>>(x, h, XH, XRH);
  k_cvt_all<<<6656, 256, 0, stream>>>(Wz, Wr, Wh, Wo, WZR, WHb, WOb);

  // GEMM 1: z|r fused (N=2048)
  k_gemm<0, 128><<<dim3(64, 16), 256, 0, stream>>>(
      XH, WZR, 2048, bz, br, h, Zb, XRH, nullptr, nullptr, nullptr);
  // GEMM 2: candidate + combine (N=1024)
  k_gemm<1, 128><<<dim3(64, 8), 256, 0, stream>>>(
      XRH, WHb, 2048, bh, nullptr, h, Zb, nullptr, outHid, HID, nullptr);
  // GEMM 3: output projection (N=512), TM=64 for a 512-block grid
  k_gemm<2, 64><<<dim3(128, 4), 256, 0, stream>>>(
      HID, WOb, 1024, bo, nullptr, nullptr, nullptr, nullptr, nullptr, nullptr,
      outO);
}